// Round 16
// baseline (143.404 us; speedup 1.0000x reference)
//
#include <hip/hip_runtime.h>
#include <math.h>

#define BB 8
#define TT 48
#define DD 512
#define NN 1024

// ---------- z = [x ; tgt_next] @ E : 64x64 tile, 4x4/thread, k-major LDS ----------
// Per-output accumulation is a single ascending-d fmaf chain over the same values
// as all prior rounds -> z is bitwise identical.
__global__ __launch_bounds__(256) void k_gemm_z(const float* __restrict__ x,
                                                const float* __restrict__ tg,
                                                const float* __restrict__ E,
                                                float* __restrict__ z_x,
                                                float* __restrict__ z_t) {
    int rt = blockIdx.x, ct = blockIdx.y;   // 12 x 16
    int tid = threadIdx.x;
    int r4 = tid >> 4;          // 0..15 row-group (4 rows)
    int c4 = tid & 15;          // 0..15 col-group (4 cols)
    int row0 = rt * 64;
    int col0 = ct * 64;

    __shared__ float As[16][68];   // [k][row]  (stride 68: 16B-aligned, bank-spread)
    __shared__ float Es[16][68];   // [k][col]

    // A staging: thread -> row ar, k-quad kq (float4 from global, 4 scalar LDS writes)
    int ar = tid >> 2;             // 0..63
    int kq = (tid & 3) * 4;        // 0,4,8,12
    int gr_s = row0 + ar;
    const float* srow;
    if (gr_s < BB * TT) {
        srow = x + (size_t)gr_s * DD;
    } else {
        int s = gr_s - BB * TT + 1;
        if (s > BB * TT - 1) s = BB * TT - 1;   // t=47 rows: garbage, masked by k_ln
        srow = tg + (size_t)s * DD;
    }

    // E staging: thread -> k = ek, cols ec..ec+3 (coalesced float4)
    int ek = tid >> 4;             // 0..15
    int ec = (tid & 15) * 4;

    float acc[4][4];
#pragma unroll
    for (int i = 0; i < 4; i++)
#pragma unroll
        for (int j = 0; j < 4; j++) acc[i][j] = 0.f;

    for (int d0 = 0; d0 < DD; d0 += 16) {
        float4 av = *reinterpret_cast<const float4*>(srow + d0 + kq);
        float4 ev = *reinterpret_cast<const float4*>(E + (size_t)(d0 + ek) * NN + col0 + ec);
        __syncthreads();
        As[kq + 0][ar] = av.x;
        As[kq + 1][ar] = av.y;
        As[kq + 2][ar] = av.z;
        As[kq + 3][ar] = av.w;
        *reinterpret_cast<float4*>(&Es[ek][ec]) = ev;
        __syncthreads();
#pragma unroll
        for (int k = 0; k < 16; k++) {
            float4 a = *reinterpret_cast<const float4*>(&As[k][r4 * 4]);
            float4 e = *reinterpret_cast<const float4*>(&Es[k][c4 * 4]);
            acc[0][0] = fmaf(a.x, e.x, acc[0][0]);
            acc[0][1] = fmaf(a.x, e.y, acc[0][1]);
            acc[0][2] = fmaf(a.x, e.z, acc[0][2]);
            acc[0][3] = fmaf(a.x, e.w, acc[0][3]);
            acc[1][0] = fmaf(a.y, e.x, acc[1][0]);
            acc[1][1] = fmaf(a.y, e.y, acc[1][1]);
            acc[1][2] = fmaf(a.y, e.z, acc[1][2]);
            acc[1][3] = fmaf(a.y, e.w, acc[1][3]);
            acc[2][0] = fmaf(a.z, e.x, acc[2][0]);
            acc[2][1] = fmaf(a.z, e.y, acc[2][1]);
            acc[2][2] = fmaf(a.z, e.z, acc[2][2]);
            acc[2][3] = fmaf(a.z, e.w, acc[2][3]);
            acc[3][0] = fmaf(a.w, e.x, acc[3][0]);
            acc[3][1] = fmaf(a.w, e.y, acc[3][1]);
            acc[3][2] = fmaf(a.w, e.z, acc[3][2]);
            acc[3][3] = fmaf(a.w, e.w, acc[3][3]);
        }
    }

    int cbase = col0 + c4 * 4;
#pragma unroll
    for (int i = 0; i < 4; i++) {
        int gr = row0 + r4 * 4 + i;
        float4 v = make_float4(acc[i][0], acc[i][1], acc[i][2], acc[i][3]);
        if (gr < BB * TT)
            *reinterpret_cast<float4*>(z_x + (size_t)gr * NN + cbase) = v;
        else
            *reinterpret_cast<float4*>(z_t + (size_t)(gr - BB * TT) * NN + cbase) = v;
    }
}

// ---------- LN + relu (round-3 exact) ----------
__global__ __launch_bounds__(256) void k_ln(const float* __restrict__ z_x,
                                            const float* __restrict__ z_t,
                                            float* __restrict__ xn,
                                            float* __restrict__ tn) {
    int bt = blockIdx.x;
    int t = bt % TT;
    int tid = threadIdx.x;
    __shared__ float rs_[256], rq_[256];

    const float* src = z_x + (size_t)bt * NN;
    float v0 = src[tid], v1 = src[tid + 256], v2 = src[tid + 512], v3 = src[tid + 768];
    rs_[tid] = v0 + v1 + v2 + v3;
    rq_[tid] = v0 * v0 + v1 * v1 + v2 * v2 + v3 * v3;
    __syncthreads();
    for (int off = 128; off > 0; off >>= 1) {
        if (tid < off) { rs_[tid] += rs_[tid + off]; rq_[tid] += rq_[tid + off]; }
        __syncthreads();
    }
    float mu = rs_[0] * (1.f / NN);
    float var = rq_[0] * (1.f / NN) - mu * mu;
    float rstd = rsqrtf(var + 1e-5f);
    float* xrow = xn + (size_t)bt * NN;
    xrow[tid]       = fmaxf((v0 - mu) * rstd, 0.f);
    xrow[tid + 256] = fmaxf((v1 - mu) * rstd, 0.f);
    xrow[tid + 512] = fmaxf((v2 - mu) * rstd, 0.f);
    xrow[tid + 768] = fmaxf((v3 - mu) * rstd, 0.f);
    __syncthreads();

    float* trow = tn + (size_t)bt * NN;
    if (t < TT - 1) {
        const float* s2 = z_t + (size_t)bt * NN;
        float u0 = s2[tid], u1 = s2[tid + 256], u2 = s2[tid + 512], u3 = s2[tid + 768];
        rs_[tid] = u0 + u1 + u2 + u3;
        rq_[tid] = u0 * u0 + u1 * u1 + u2 * u2 + u3 * u3;
        __syncthreads();
        for (int off = 128; off > 0; off >>= 1) {
            if (tid < off) { rs_[tid] += rs_[tid + off]; rq_[tid] += rq_[tid + off]; }
            __syncthreads();
        }
        float mu2 = rs_[0] * (1.f / NN);
        float var2 = rq_[0] * (1.f / NN) - mu2 * mu2;
        float r2 = rsqrtf(var2 + 1e-5f);
        trow[tid]       = fmaxf((u0 - mu2) * r2, 0.f);
        trow[tid + 256] = fmaxf((u1 - mu2) * r2, 0.f);
        trow[tid + 512] = fmaxf((u2 - mu2) * r2, 0.f);
        trow[tid + 768] = fmaxf((u3 - mu2) * r2, 0.f);
    } else {
        trow[tid] = 0.f; trow[tid + 256] = 0.f; trow[tid + 512] = 0.f; trow[tid + 768] = 0.f;
    }
}

// ---------- the recurrence: G in arch VGPRs, weights via SMEM ping-pong (round-15 exact) ----------
typedef __attribute__((ext_vector_type(16))) float f16v;

#define GI(n) float g##n = (state == 0 && nc == cc && (n) == lane) ? 0.5f : 0.f;
#define REP64(X) X(0) X(1) X(2) X(3) X(4) X(5) X(6) X(7) X(8) X(9) X(10) X(11) X(12) X(13) \
    X(14) X(15) X(16) X(17) X(18) X(19) X(20) X(21) X(22) X(23) X(24) X(25) X(26) X(27) \
    X(28) X(29) X(30) X(31) X(32) X(33) X(34) X(35) X(36) X(37) X(38) X(39) X(40) X(41) \
    X(42) X(43) X(44) X(45) X(46) X(47) X(48) X(49) X(50) X(51) X(52) X(53) X(54) X(55) \
    X(56) X(57) X(58) X(59) X(60) X(61) X(62) X(63)

#define GS(W, I, n, A) { float wn_ = (W)[I]; float tmp_;                         \
    asm("v_fmac_f32 %[a], %[w], %[g]\n\t"                                        \
        "v_mul_f32 %[t], %[w], %[m]\n\t"                                         \
        "v_max_f32 %[g], %[g], %[t]"                                             \
        : [a]"+v"(A), [g]"+v"(g##n), [t]"=&v"(tmp_)                              \
        : [w]"s"(wn_), [m]"v"(mh)); }

__global__ __launch_bounds__(256)
__attribute__((amdgpu_waves_per_eu(2, 4)))
void k_sweep(const float* __restrict__ xn,
             const float* __restrict__ tn,
             float* __restrict__ r_part) {
    int bid = blockIdx.x;
    int ccg = bid & 3, nc = (bid >> 2) & 15, b = (bid >> 6) & 7, state = bid >> 9;
    int tid = threadIdx.x;
    int lane = tid & 63;
    int wid = __builtin_amdgcn_readfirstlane(tid >> 6);
    int cc = ccg * 4 + wid;
    int n0 = nc * 64;
    int col = cc * 64 + lane;

    REP64(GI)

    const float* wb  = xn + (size_t)b * TT * NN + n0;              // wave-uniform rows
    const float* mvb = (state ? tn : xn) + (size_t)b * TT * NN + col;
    float* rp = r_part + ((size_t)((state * 8 + b) * 16 + nc) * TT) * NN + col;

    f16v H1a, H1b, H2a, H2b;
    asm volatile("s_load_dwordx16 %0, %2, 0x0\n\t"
                 "s_load_dwordx16 %1, %2, 0x40"
                 : "=s"(H1a), "=s"(H1b) : "s"(wb));

    float mv_cur = mvb[0];

#pragma unroll 1
    for (int t = 0; t < TT; t++) {
        const float* xrow = wb + (size_t)t * NN;
        int tn1 = (t + 1 < TT) ? t + 1 : TT - 1;
        const float* xrow_n = wb + (size_t)tn1 * NN;
        float mv_nxt = mvb[(size_t)tn1 * NN];
        float sc = (t < TT - 1) ? 0.5f : 0.0f;
        float mh = mv_cur * sc;
        float a0 = 0.f, a1 = 0.f, a2 = 0.f, a3 = 0.f;

        asm volatile("s_waitcnt lgkmcnt(0)" : "+s"(H1a), "+s"(H1b));
        asm volatile("s_load_dwordx16 %0, %2, 0x80\n\t"
                     "s_load_dwordx16 %1, %2, 0xc0"
                     : "=s"(H2a), "=s"(H2b) : "s"(xrow));

        GS(H1a,0,0,a0)   GS(H1a,1,1,a1)   GS(H1a,2,2,a2)   GS(H1a,3,3,a3)
        GS(H1a,4,4,a0)   GS(H1a,5,5,a1)   GS(H1a,6,6,a2)   GS(H1a,7,7,a3)
        GS(H1a,8,8,a0)   GS(H1a,9,9,a1)   GS(H1a,10,10,a2) GS(H1a,11,11,a3)
        GS(H1a,12,12,a0) GS(H1a,13,13,a1) GS(H1a,14,14,a2) GS(H1a,15,15,a3)
        GS(H1b,0,16,a0)  GS(H1b,1,17,a1)  GS(H1b,2,18,a2)  GS(H1b,3,19,a3)
        GS(H1b,4,20,a0)  GS(H1b,5,21,a1)  GS(H1b,6,22,a2)  GS(H1b,7,23,a3)
        GS(H1b,8,24,a0)  GS(H1b,9,25,a1)  GS(H1b,10,26,a2) GS(H1b,11,27,a3)
        GS(H1b,12,28,a0) GS(H1b,13,29,a1) GS(H1b,14,30,a2) GS(H1b,15,31,a3)

        asm volatile("s_waitcnt lgkmcnt(0)"
                     : "+s"(H2a), "+s"(H2b), "+v"(a0), "+v"(a1), "+v"(a2), "+v"(a3));
        asm volatile("s_load_dwordx16 %0, %2, 0x0\n\t"
                     "s_load_dwordx16 %1, %2, 0x40"
                     : "=s"(H1a), "=s"(H1b) : "s"(xrow_n));

        GS(H2a,0,32,a0)  GS(H2a,1,33,a1)  GS(H2a,2,34,a2)  GS(H2a,3,35,a3)
        GS(H2a,4,36,a0)  GS(H2a,5,37,a1)  GS(H2a,6,38,a2)  GS(H2a,7,39,a3)
        GS(H2a,8,40,a0)  GS(H2a,9,41,a1)  GS(H2a,10,42,a2) GS(H2a,11,43,a3)
        GS(H2a,12,44,a0) GS(H2a,13,45,a1) GS(H2a,14,46,a2) GS(H2a,15,47,a3)
        GS(H2b,0,48,a0)  GS(H2b,1,49,a1)  GS(H2b,2,50,a2)  GS(H2b,3,51,a3)
        GS(H2b,4,52,a0)  GS(H2b,5,53,a1)  GS(H2b,6,54,a2)  GS(H2b,7,55,a3)
        GS(H2b,8,56,a0)  GS(H2b,9,57,a1)  GS(H2b,10,58,a2) GS(H2b,11,59,a3)
        GS(H2b,12,60,a0) GS(H2b,13,61,a1) GS(H2b,14,62,a2) GS(H2b,15,63,a3)

        rp[(size_t)t * NN] = (a0 + a1) + (a2 + a3);
        mv_cur = mv_nxt;
    }
}

// ---------- reduce partials over nc + mix (round-11 exact) ----------
__global__ __launch_bounds__(256) void k_mix(const float* __restrict__ r_part,
                                             const float* __restrict__ mixp,
                                             float* __restrict__ mix) {
    int bt = blockIdx.x;            // b*TT + t
    int b = bt / TT, t = bt % TT;
    int tid = threadIdx.x;
    int c0 = tid * 4;
    float alpha = 1.f / (1.f + expf(-mixp[0]));

    float spx = 0.f, spy = 0.f, spz = 0.f, spw = 0.f;
    float stx = 0.f, sty = 0.f, stz = 0.f, stw = 0.f;
#pragma unroll
    for (int nc = 0; nc < 16; nc++) {
        int bidp = (b * 16 + nc);
        int bidt = ((8 + b) * 16 + nc);
        float4 p = *reinterpret_cast<const float4*>(r_part + ((size_t)bidp * TT + t) * NN + c0);
        float4 q = *reinterpret_cast<const float4*>(r_part + ((size_t)bidt * TT + t) * NN + c0);
        spx += p.x; spy += p.y; spz += p.z; spw += p.w;
        stx += q.x; sty += q.y; stz += q.z; stw += q.w;
    }
    float4 m4;
    m4.x = alpha * spx + (1.f - alpha) * stx;
    m4.y = alpha * spy + (1.f - alpha) * sty;
    m4.z = alpha * spz + (1.f - alpha) * stz;
    m4.w = alpha * spw + (1.f - alpha) * stw;
    *reinterpret_cast<float4*>(mix + (size_t)bt * NN + c0) = m4;
}

// ---------- y = relu(mix @ Dy) (round-11 exact) ----------
__global__ __launch_bounds__(256) void k_y2(const float* __restrict__ mix,
                                            const float* __restrict__ Dy,
                                            float* __restrict__ out) {
    int ct = blockIdx.x;            // 0..7
    int rt = blockIdx.y;            // 0..23
    int tid = threadIdx.x;
    int row0 = rt * 16;
    int col0 = ct * 64;
    int r = tid >> 4;               // 0..15
    int tc = tid & 15;              // 0..15

    __shared__ float As[16][16];
    __shared__ float Ds[16][64];

    int sr = tid >> 4, sk = tid & 15;
    int se = tid >> 4, sc0 = (tid & 15) * 4;

    float4 acc = make_float4(0.f, 0.f, 0.f, 0.f);

    for (int m0 = 0; m0 < NN; m0 += 16) {
        float av = mix[(size_t)(row0 + sr) * NN + m0 + sk];
        float4 dv = *reinterpret_cast<const float4*>(Dy + (size_t)(m0 + se) * DD + col0 + sc0);
        __syncthreads();
        As[sr][sk] = av;
        *reinterpret_cast<float4*>(&Ds[se][sc0]) = dv;
        __syncthreads();
#pragma unroll
        for (int k = 0; k < 16; k++) {
            float a = As[r][k];
            float4 e = *reinterpret_cast<const float4*>(&Ds[k][tc * 4]);
            acc.x = fmaf(a, e.x, acc.x);
            acc.y = fmaf(a, e.y, acc.y);
            acc.z = fmaf(a, e.z, acc.z);
            acc.w = fmaf(a, e.w, acc.w);
        }
    }

    float4 o = make_float4(fmaxf(acc.x, 0.f), fmaxf(acc.y, 0.f),
                           fmaxf(acc.z, 0.f), fmaxf(acc.w, 0.f));
    *reinterpret_cast<float4*>(out + (size_t)(row0 + r) * DD + col0 + tc * 4) = o;
}

extern "C" void kernel_launch(void* const* d_in, const int* in_sizes, int n_in,
                              void* d_out, int out_size, void* d_ws, size_t ws_size,
                              hipStream_t stream) {
    const float* x    = (const float*)d_in[0];   // [8,48,512]
    const float* tg   = (const float*)d_in[1];   // [8,48,512]
    const float* E    = (const float*)d_in[2];   // [512,1024]
    const float* Dy   = (const float*)d_in[3];   // [1024,512]
    const float* mixp = (const float*)d_in[4];   // scalar
    float* out = (float*)d_out;                  // [8,48,512]

    float* ws = (float*)d_ws;
    float* z_x    = ws;                               // 384*1024
    float* z_t    = z_x + (size_t)384 * 1024;
    float* xn     = z_t + (size_t)384 * 1024;
    float* tn     = xn + (size_t)384 * 1024;
    float* r_part = tn + (size_t)384 * 1024;          // 256 chunks * 48 * 1024 floats
    float* mixbuf = r_part + (size_t)256 * 48 * 1024; // 384*1024

    k_gemm_z<<<dim3(12, 16), 256, 0, stream>>>(x, tg, E, z_x, z_t);
    k_ln<<<384, 256, 0, stream>>>(z_x, z_t, xn, tn);
    k_sweep<<<1024, 256, 0, stream>>>(xn, tn, r_part);
    k_mix<<<384, 256, 0, stream>>>(r_part, mixp, mixbuf);
    k_y2<<<dim3(8, 24), 256, 0, stream>>>(mixbuf, Dy, out);
}

// Round 17
// 143.102 us; speedup vs baseline: 1.0021x; 1.0021x over previous
//
#include <hip/hip_runtime.h>
#include <math.h>

#define BB 8
#define TT 48
#define DD 512
#define NN 1024

// ---------- z = [x ; tgt_next] @ E : 64x64 tile, 4x4/thread, k-major LDS (round-16 exact) ----------
__global__ __launch_bounds__(256) void k_gemm_z(const float* __restrict__ x,
                                                const float* __restrict__ tg,
                                                const float* __restrict__ E,
                                                float* __restrict__ z_x,
                                                float* __restrict__ z_t) {
    int rt = blockIdx.x, ct = blockIdx.y;   // 12 x 16
    int tid = threadIdx.x;
    int r4 = tid >> 4;
    int c4 = tid & 15;
    int row0 = rt * 64;
    int col0 = ct * 64;

    __shared__ float As[16][68];
    __shared__ float Es[16][68];

    int ar = tid >> 2;
    int kq = (tid & 3) * 4;
    int gr_s = row0 + ar;
    const float* srow;
    if (gr_s < BB * TT) {
        srow = x + (size_t)gr_s * DD;
    } else {
        int s = gr_s - BB * TT + 1;
        if (s > BB * TT - 1) s = BB * TT - 1;   // t=47 rows: garbage, masked by k_ln
        srow = tg + (size_t)s * DD;
    }

    int ek = tid >> 4;
    int ec = (tid & 15) * 4;

    float acc[4][4];
#pragma unroll
    for (int i = 0; i < 4; i++)
#pragma unroll
        for (int j = 0; j < 4; j++) acc[i][j] = 0.f;

    for (int d0 = 0; d0 < DD; d0 += 16) {
        float4 av = *reinterpret_cast<const float4*>(srow + d0 + kq);
        float4 ev = *reinterpret_cast<const float4*>(E + (size_t)(d0 + ek) * NN + col0 + ec);
        __syncthreads();
        As[kq + 0][ar] = av.x;
        As[kq + 1][ar] = av.y;
        As[kq + 2][ar] = av.z;
        As[kq + 3][ar] = av.w;
        *reinterpret_cast<float4*>(&Es[ek][ec]) = ev;
        __syncthreads();
#pragma unroll
        for (int k = 0; k < 16; k++) {
            float4 a = *reinterpret_cast<const float4*>(&As[k][r4 * 4]);
            float4 e = *reinterpret_cast<const float4*>(&Es[k][c4 * 4]);
            acc[0][0] = fmaf(a.x, e.x, acc[0][0]);
            acc[0][1] = fmaf(a.x, e.y, acc[0][1]);
            acc[0][2] = fmaf(a.x, e.z, acc[0][2]);
            acc[0][3] = fmaf(a.x, e.w, acc[0][3]);
            acc[1][0] = fmaf(a.y, e.x, acc[1][0]);
            acc[1][1] = fmaf(a.y, e.y, acc[1][1]);
            acc[1][2] = fmaf(a.y, e.z, acc[1][2]);
            acc[1][3] = fmaf(a.y, e.w, acc[1][3]);
            acc[2][0] = fmaf(a.z, e.x, acc[2][0]);
            acc[2][1] = fmaf(a.z, e.y, acc[2][1]);
            acc[2][2] = fmaf(a.z, e.z, acc[2][2]);
            acc[2][3] = fmaf(a.z, e.w, acc[2][3]);
            acc[3][0] = fmaf(a.w, e.x, acc[3][0]);
            acc[3][1] = fmaf(a.w, e.y, acc[3][1]);
            acc[3][2] = fmaf(a.w, e.z, acc[3][2]);
            acc[3][3] = fmaf(a.w, e.w, acc[3][3]);
        }
    }

    int cbase = col0 + c4 * 4;
#pragma unroll
    for (int i = 0; i < 4; i++) {
        int gr = row0 + r4 * 4 + i;
        float4 v = make_float4(acc[i][0], acc[i][1], acc[i][2], acc[i][3]);
        if (gr < BB * TT)
            *reinterpret_cast<float4*>(z_x + (size_t)gr * NN + cbase) = v;
        else
            *reinterpret_cast<float4*>(z_t + (size_t)(gr - BB * TT) * NN + cbase) = v;
    }
}

// ---------- LN + relu (round-3 exact) ----------
__global__ __launch_bounds__(256) void k_ln(const float* __restrict__ z_x,
                                            const float* __restrict__ z_t,
                                            float* __restrict__ xn,
                                            float* __restrict__ tn) {
    int bt = blockIdx.x;
    int t = bt % TT;
    int tid = threadIdx.x;
    __shared__ float rs_[256], rq_[256];

    const float* src = z_x + (size_t)bt * NN;
    float v0 = src[tid], v1 = src[tid + 256], v2 = src[tid + 512], v3 = src[tid + 768];
    rs_[tid] = v0 + v1 + v2 + v3;
    rq_[tid] = v0 * v0 + v1 * v1 + v2 * v2 + v3 * v3;
    __syncthreads();
    for (int off = 128; off > 0; off >>= 1) {
        if (tid < off) { rs_[tid] += rs_[tid + off]; rq_[tid] += rq_[tid + off]; }
        __syncthreads();
    }
    float mu = rs_[0] * (1.f / NN);
    float var = rq_[0] * (1.f / NN) - mu * mu;
    float rstd = rsqrtf(var + 1e-5f);
    float* xrow = xn + (size_t)bt * NN;
    xrow[tid]       = fmaxf((v0 - mu) * rstd, 0.f);
    xrow[tid + 256] = fmaxf((v1 - mu) * rstd, 0.f);
    xrow[tid + 512] = fmaxf((v2 - mu) * rstd, 0.f);
    xrow[tid + 768] = fmaxf((v3 - mu) * rstd, 0.f);
    __syncthreads();

    float* trow = tn + (size_t)bt * NN;
    if (t < TT - 1) {
        const float* s2 = z_t + (size_t)bt * NN;
        float u0 = s2[tid], u1 = s2[tid + 256], u2 = s2[tid + 512], u3 = s2[tid + 768];
        rs_[tid] = u0 + u1 + u2 + u3;
        rq_[tid] = u0 * u0 + u1 * u1 + u2 * u2 + u3 * u3;
        __syncthreads();
        for (int off = 128; off > 0; off >>= 1) {
            if (tid < off) { rs_[tid] += rs_[tid + off]; rq_[tid] += rq_[tid + off]; }
            __syncthreads();
        }
        float mu2 = rs_[0] * (1.f / NN);
        float var2 = rq_[0] * (1.f / NN) - mu2 * mu2;
        float r2 = rsqrtf(var2 + 1e-5f);
        trow[tid]       = fmaxf((u0 - mu2) * r2, 0.f);
        trow[tid + 256] = fmaxf((u1 - mu2) * r2, 0.f);
        trow[tid + 512] = fmaxf((u2 - mu2) * r2, 0.f);
        trow[tid + 768] = fmaxf((u3 - mu2) * r2, 0.f);
    } else {
        trow[tid] = 0.f; trow[tid + 256] = 0.f; trow[tid + 512] = 0.f; trow[tid + 768] = 0.f;
    }
}

// ---------- the recurrence: SMEM ping-pong weights + round-3-validated 4-wave tree ----------
// 1024 blocks: bid = state<<9 | b<<6 | ng<<4 | cc. Wave wid -> row chunk nc=ng*4+wid;
// all 4 waves share col chunk cc. Per t: parity-buffered LDS tree reduce over the 4
// waves (order (r0+r64)+(r128+r192), ascending nc) -> r_part shrinks 4x to 12.5 MB.
// This exact summation order passed both checks in round 3 (absmax 8.0).

typedef __attribute__((ext_vector_type(16))) float f16v;

#define GI(n) float g##n = (state == 0 && nc == cc && (n) == lane) ? 0.5f : 0.f;
#define REP64(X) X(0) X(1) X(2) X(3) X(4) X(5) X(6) X(7) X(8) X(9) X(10) X(11) X(12) X(13) \
    X(14) X(15) X(16) X(17) X(18) X(19) X(20) X(21) X(22) X(23) X(24) X(25) X(26) X(27) \
    X(28) X(29) X(30) X(31) X(32) X(33) X(34) X(35) X(36) X(37) X(38) X(39) X(40) X(41) \
    X(42) X(43) X(44) X(45) X(46) X(47) X(48) X(49) X(50) X(51) X(52) X(53) X(54) X(55) \
    X(56) X(57) X(58) X(59) X(60) X(61) X(62) X(63)

#define GS(W, I, n, A) { float wn_ = (W)[I]; float tmp_;                         \
    asm("v_fmac_f32 %[a], %[w], %[g]\n\t"                                        \
        "v_mul_f32 %[t], %[w], %[m]\n\t"                                         \
        "v_max_f32 %[g], %[g], %[t]"                                             \
        : [a]"+v"(A), [g]"+v"(g##n), [t]"=&v"(tmp_)                              \
        : [w]"s"(wn_), [m]"v"(mh)); }

__global__ __launch_bounds__(256)
__attribute__((amdgpu_waves_per_eu(2, 4)))
void k_sweep(const float* __restrict__ xn,
             const float* __restrict__ tn,
             float* __restrict__ r_part) {
    int bid = blockIdx.x;
    int cc = bid & 15, ng = (bid >> 4) & 3, b = (bid >> 6) & 7, state = bid >> 9;
    int tid = threadIdx.x;
    int lane = tid & 63;
    int wid = __builtin_amdgcn_readfirstlane(tid >> 6);
    int nc = ng * 4 + wid;                  // wave's row chunk
    int col = cc * 64 + lane;

    __shared__ float red[2][256];

    REP64(GI)

    const float* wb  = xn + (size_t)b * TT * NN + nc * 64;         // wave-uniform rows
    const float* mvb = (state ? tn : xn) + (size_t)b * TT * NN + col;
    float* rp = r_part + ((size_t)((state * 8 + b) * 4 + ng) * TT) * NN + col;

    f16v H1a, H1b, H2a, H2b;
    asm volatile("s_load_dwordx16 %0, %2, 0x0\n\t"
                 "s_load_dwordx16 %1, %2, 0x40"
                 : "=s"(H1a), "=s"(H1b) : "s"(wb));

    float mv_cur = mvb[0];

#pragma unroll 1
    for (int t = 0; t < TT; t++) {
        const float* xrow = wb + (size_t)t * NN;
        int tn1 = (t + 1 < TT) ? t + 1 : TT - 1;
        const float* xrow_n = wb + (size_t)tn1 * NN;
        float mv_nxt = mvb[(size_t)tn1 * NN];
        float sc = (t < TT - 1) ? 0.5f : 0.0f;
        float mh = mv_cur * sc;
        float a0 = 0.f, a1 = 0.f, a2 = 0.f, a3 = 0.f;

        asm volatile("s_waitcnt lgkmcnt(0)" : "+s"(H1a), "+s"(H1b));
        asm volatile("s_load_dwordx16 %0, %2, 0x80\n\t"
                     "s_load_dwordx16 %1, %2, 0xc0"
                     : "=s"(H2a), "=s"(H2b) : "s"(xrow));

        GS(H1a,0,0,a0)   GS(H1a,1,1,a1)   GS(H1a,2,2,a2)   GS(H1a,3,3,a3)
        GS(H1a,4,4,a0)   GS(H1a,5,5,a1)   GS(H1a,6,6,a2)   GS(H1a,7,7,a3)
        GS(H1a,8,8,a0)   GS(H1a,9,9,a1)   GS(H1a,10,10,a2) GS(H1a,11,11,a3)
        GS(H1a,12,12,a0) GS(H1a,13,13,a1) GS(H1a,14,14,a2) GS(H1a,15,15,a3)
        GS(H1b,0,16,a0)  GS(H1b,1,17,a1)  GS(H1b,2,18,a2)  GS(H1b,3,19,a3)
        GS(H1b,4,20,a0)  GS(H1b,5,21,a1)  GS(H1b,6,22,a2)  GS(H1b,7,23,a3)
        GS(H1b,8,24,a0)  GS(H1b,9,25,a1)  GS(H1b,10,26,a2) GS(H1b,11,27,a3)
        GS(H1b,12,28,a0) GS(H1b,13,29,a1) GS(H1b,14,30,a2) GS(H1b,15,31,a3)

        asm volatile("s_waitcnt lgkmcnt(0)"
                     : "+s"(H2a), "+s"(H2b), "+v"(a0), "+v"(a1), "+v"(a2), "+v"(a3));
        asm volatile("s_load_dwordx16 %0, %2, 0x0\n\t"
                     "s_load_dwordx16 %1, %2, 0x40"
                     : "=s"(H1a), "=s"(H1b) : "s"(xrow_n));

        GS(H2a,0,32,a0)  GS(H2a,1,33,a1)  GS(H2a,2,34,a2)  GS(H2a,3,35,a3)
        GS(H2a,4,36,a0)  GS(H2a,5,37,a1)  GS(H2a,6,38,a2)  GS(H2a,7,39,a3)
        GS(H2a,8,40,a0)  GS(H2a,9,41,a1)  GS(H2a,10,42,a2) GS(H2a,11,43,a3)
        GS(H2a,12,44,a0) GS(H2a,13,45,a1) GS(H2a,14,46,a2) GS(H2a,15,47,a3)
        GS(H2b,0,48,a0)  GS(H2b,1,49,a1)  GS(H2b,2,50,a2)  GS(H2b,3,51,a3)
        GS(H2b,4,52,a0)  GS(H2b,5,53,a1)  GS(H2b,6,54,a2)  GS(H2b,7,55,a3)
        GS(H2b,8,56,a0)  GS(H2b,9,57,a1)  GS(H2b,10,58,a2) GS(H2b,11,59,a3)
        GS(H2b,12,60,a0) GS(H2b,13,61,a1) GS(H2b,14,62,a2) GS(H2b,15,63,a3)

        red[t & 1][tid] = (a0 + a1) + (a2 + a3);
        __syncthreads();
        if (wid == 0) {
            const float* r = red[t & 1];
            rp[(size_t)t * NN] = (r[lane] + r[64 + lane]) + (r[128 + lane] + r[192 + lane]);
        }
        mv_cur = mv_nxt;
    }
}

// ---------- reduce partials over ng + mix (round-3-validated order) ----------
__global__ __launch_bounds__(256) void k_mix(const float* __restrict__ r_part,
                                             const float* __restrict__ mixp,
                                             float* __restrict__ mix) {
    int bt = blockIdx.x;            // b*TT + t
    int b = bt / TT, t = bt % TT;
    int tid = threadIdx.x;
    int c0 = tid * 4;
    float alpha = 1.f / (1.f + expf(-mixp[0]));

    float spx = 0.f, spy = 0.f, spz = 0.f, spw = 0.f;
    float stx = 0.f, sty = 0.f, stz = 0.f, stw = 0.f;
#pragma unroll
    for (int ng = 0; ng < 4; ng++) {
        int bidp = (b * 4 + ng);
        int bidt = ((8 + b) * 4 + ng);
        float4 p = *reinterpret_cast<const float4*>(r_part + ((size_t)bidp * TT + t) * NN + c0);
        float4 q = *reinterpret_cast<const float4*>(r_part + ((size_t)bidt * TT + t) * NN + c0);
        spx += p.x; spy += p.y; spz += p.z; spw += p.w;
        stx += q.x; sty += q.y; stz += q.z; stw += q.w;
    }
    float4 m4;
    m4.x = alpha * spx + (1.f - alpha) * stx;
    m4.y = alpha * spy + (1.f - alpha) * sty;
    m4.z = alpha * spz + (1.f - alpha) * stz;
    m4.w = alpha * spw + (1.f - alpha) * stw;
    *reinterpret_cast<float4*>(mix + (size_t)bt * NN + c0) = m4;
}

// ---------- y = relu(mix @ Dy) (round-11 exact) ----------
__global__ __launch_bounds__(256) void k_y2(const float* __restrict__ mix,
                                            const float* __restrict__ Dy,
                                            float* __restrict__ out) {
    int ct = blockIdx.x;            // 0..7
    int rt = blockIdx.y;            // 0..23
    int tid = threadIdx.x;
    int row0 = rt * 16;
    int col0 = ct * 64;
    int r = tid >> 4;
    int tc = tid & 15;

    __shared__ float As[16][16];
    __shared__ float Ds[16][64];

    int sr = tid >> 4, sk = tid & 15;
    int se = tid >> 4, sc0 = (tid & 15) * 4;

    float4 acc = make_float4(0.f, 0.f, 0.f, 0.f);

    for (int m0 = 0; m0 < NN; m0 += 16) {
        float av = mix[(size_t)(row0 + sr) * NN + m0 + sk];
        float4 dv = *reinterpret_cast<const float4*>(Dy + (size_t)(m0 + se) * DD + col0 + sc0);
        __syncthreads();
        As[sr][sk] = av;
        *reinterpret_cast<float4*>(&Ds[se][sc0]) = dv;
        __syncthreads();
#pragma unroll
        for (int k = 0; k < 16; k++) {
            float a = As[r][k];
            float4 e = *reinterpret_cast<const float4*>(&Ds[k][tc * 4]);
            acc.x = fmaf(a, e.x, acc.x);
            acc.y = fmaf(a, e.y, acc.y);
            acc.z = fmaf(a, e.z, acc.z);
            acc.w = fmaf(a, e.w, acc.w);
        }
    }

    float4 o = make_float4(fmaxf(acc.x, 0.f), fmaxf(acc.y, 0.f),
                           fmaxf(acc.z, 0.f), fmaxf(acc.w, 0.f));
    *reinterpret_cast<float4*>(out + (size_t)(row0 + r) * DD + col0 + tc * 4) = o;
}

extern "C" void kernel_launch(void* const* d_in, const int* in_sizes, int n_in,
                              void* d_out, int out_size, void* d_ws, size_t ws_size,
                              hipStream_t stream) {
    const float* x    = (const float*)d_in[0];   // [8,48,512]
    const float* tg   = (const float*)d_in[1];   // [8,48,512]
    const float* E    = (const float*)d_in[2];   // [512,1024]
    const float* Dy   = (const float*)d_in[3];   // [1024,512]
    const float* mixp = (const float*)d_in[4];   // scalar
    float* out = (float*)d_out;                  // [8,48,512]

    float* ws = (float*)d_ws;
    float* z_x    = ws;                               // 384*1024
    float* z_t    = z_x + (size_t)384 * 1024;
    float* xn     = z_t + (size_t)384 * 1024;
    float* tn     = xn + (size_t)384 * 1024;
    float* r_part = tn + (size_t)384 * 1024;          // 64 chunks * 48 * 1024 floats
    float* mixbuf = r_part + (size_t)64 * 48 * 1024;  // 384*1024

    k_gemm_z<<<dim3(12, 16), 256, 0, stream>>>(x, tg, E, z_x, z_t);
    k_ln<<<384, 256, 0, stream>>>(z_x, z_t, xn, tn);
    k_sweep<<<1024, 256, 0, stream>>>(xn, tn, r_part);
    k_mix<<<384, 256, 0, stream>>>(r_part, mixp, mixbuf);
    k_y2<<<dim3(8, 24), 256, 0, stream>>>(mixbuf, Dy, out);
}

// Round 18
// 138.482 us; speedup vs baseline: 1.0355x; 1.0334x over previous
//
#include <hip/hip_runtime.h>
#include <math.h>

#define BB 8
#define TT 48
#define DD 512
#define NN 1024

// ---------- z = [x ; tgt_next] @ E, LDS-tiled (round-9 exact; best measured) ----------
__global__ __launch_bounds__(256) void k_gemm_z(const float* __restrict__ x,
                                                const float* __restrict__ tg,
                                                const float* __restrict__ E,
                                                float* __restrict__ z_x,
                                                float* __restrict__ z_t) {
    int rt = blockIdx.x, ct = blockIdx.y;   // 24 x 16
    int tid = threadIdx.x;
    int tr = tid >> 4;          // 0..15
    int tc = tid & 15;          // 0..15
    int row0 = rt * 32;
    int col0 = ct * 64;

    __shared__ float As[32][16];
    __shared__ float Es[16][64];

    int e2 = tid * 2;
    int sr = e2 >> 4;           // 0..31
    int sk0 = e2 & 15;
    int gr_s = row0 + sr;
    const float* srow;
    if (gr_s < BB * TT) {
        srow = x + (size_t)gr_s * DD;
    } else {
        int s = gr_s - BB * TT + 1;
        if (s > BB * TT - 1) s = BB * TT - 1;   // t=47 rows: garbage, masked by k_ln
        srow = tg + (size_t)s * DD;
    }

    int se = tid >> 4;          // 0..15
    int sc0 = (tid & 15) * 4;
    const float* erow = E + col0 + sc0;

    float4 acc0 = make_float4(0.f, 0.f, 0.f, 0.f);
    float4 acc1 = make_float4(0.f, 0.f, 0.f, 0.f);

    for (int d0 = 0; d0 < DD; d0 += 16) {
        float2 xv = *reinterpret_cast<const float2*>(srow + d0 + sk0);
        float4 ev = *reinterpret_cast<const float4*>(erow + (size_t)(d0 + se) * NN);
        __syncthreads();
        As[sr][sk0] = xv.x;
        As[sr][sk0 + 1] = xv.y;
        *reinterpret_cast<float4*>(&Es[se][sc0]) = ev;
        __syncthreads();
#pragma unroll
        for (int k = 0; k < 16; k++) {
            float a0 = As[tr][k];
            float a1 = As[tr + 16][k];
            float4 e = *reinterpret_cast<const float4*>(&Es[k][tc * 4]);
            acc0.x = fmaf(a0, e.x, acc0.x);
            acc0.y = fmaf(a0, e.y, acc0.y);
            acc0.z = fmaf(a0, e.z, acc0.z);
            acc0.w = fmaf(a0, e.w, acc0.w);
            acc1.x = fmaf(a1, e.x, acc1.x);
            acc1.y = fmaf(a1, e.y, acc1.y);
            acc1.z = fmaf(a1, e.z, acc1.z);
            acc1.w = fmaf(a1, e.w, acc1.w);
        }
    }

    int gr0 = row0 + tr, gr1 = row0 + tr + 16;
    int cbase = col0 + tc * 4;
    if (gr0 < BB * TT)
        *reinterpret_cast<float4*>(z_x + (size_t)gr0 * NN + cbase) = acc0;
    else
        *reinterpret_cast<float4*>(z_t + (size_t)(gr0 - BB * TT) * NN + cbase) = acc0;
    if (gr1 < BB * TT)
        *reinterpret_cast<float4*>(z_x + (size_t)gr1 * NN + cbase) = acc1;
    else
        *reinterpret_cast<float4*>(z_t + (size_t)(gr1 - BB * TT) * NN + cbase) = acc1;
}

// ---------- LN + relu (round-3 exact) ----------
__global__ __launch_bounds__(256) void k_ln(const float* __restrict__ z_x,
                                            const float* __restrict__ z_t,
                                            float* __restrict__ xn,
                                            float* __restrict__ tn) {
    int bt = blockIdx.x;
    int t = bt % TT;
    int tid = threadIdx.x;
    __shared__ float rs_[256], rq_[256];

    const float* src = z_x + (size_t)bt * NN;
    float v0 = src[tid], v1 = src[tid + 256], v2 = src[tid + 512], v3 = src[tid + 768];
    rs_[tid] = v0 + v1 + v2 + v3;
    rq_[tid] = v0 * v0 + v1 * v1 + v2 * v2 + v3 * v3;
    __syncthreads();
    for (int off = 128; off > 0; off >>= 1) {
        if (tid < off) { rs_[tid] += rs_[tid + off]; rq_[tid] += rq_[tid + off]; }
        __syncthreads();
    }
    float mu = rs_[0] * (1.f / NN);
    float var = rq_[0] * (1.f / NN) - mu * mu;
    float rstd = rsqrtf(var + 1e-5f);
    float* xrow = xn + (size_t)bt * NN;
    xrow[tid]       = fmaxf((v0 - mu) * rstd, 0.f);
    xrow[tid + 256] = fmaxf((v1 - mu) * rstd, 0.f);
    xrow[tid + 512] = fmaxf((v2 - mu) * rstd, 0.f);
    xrow[tid + 768] = fmaxf((v3 - mu) * rstd, 0.f);
    __syncthreads();

    float* trow = tn + (size_t)bt * NN;
    if (t < TT - 1) {
        const float* s2 = z_t + (size_t)bt * NN;
        float u0 = s2[tid], u1 = s2[tid + 256], u2 = s2[tid + 512], u3 = s2[tid + 768];
        rs_[tid] = u0 + u1 + u2 + u3;
        rq_[tid] = u0 * u0 + u1 * u1 + u2 * u2 + u3 * u3;
        __syncthreads();
        for (int off = 128; off > 0; off >>= 1) {
            if (tid < off) { rs_[tid] += rs_[tid + off]; rq_[tid] += rq_[tid + off]; }
            __syncthreads();
        }
        float mu2 = rs_[0] * (1.f / NN);
        float var2 = rq_[0] * (1.f / NN) - mu2 * mu2;
        float r2 = rsqrtf(var2 + 1e-5f);
        trow[tid]       = fmaxf((u0 - mu2) * r2, 0.f);
        trow[tid + 256] = fmaxf((u1 - mu2) * r2, 0.f);
        trow[tid + 512] = fmaxf((u2 - mu2) * r2, 0.f);
        trow[tid + 768] = fmaxf((u3 - mu2) * r2, 0.f);
    } else {
        trow[tid] = 0.f; trow[tid + 256] = 0.f; trow[tid + 512] = 0.f; trow[tid + 768] = 0.f;
    }
}

// ---------- the recurrence: SMEM ping-pong weights + 4-wave tree (round-17 exact) ----------
typedef __attribute__((ext_vector_type(16))) float f16v;

#define GI(n) float g##n = (state == 0 && nc == cc && (n) == lane) ? 0.5f : 0.f;
#define REP64(X) X(0) X(1) X(2) X(3) X(4) X(5) X(6) X(7) X(8) X(9) X(10) X(11) X(12) X(13) \
    X(14) X(15) X(16) X(17) X(18) X(19) X(20) X(21) X(22) X(23) X(24) X(25) X(26) X(27) \
    X(28) X(29) X(30) X(31) X(32) X(33) X(34) X(35) X(36) X(37) X(38) X(39) X(40) X(41) \
    X(42) X(43) X(44) X(45) X(46) X(47) X(48) X(49) X(50) X(51) X(52) X(53) X(54) X(55) \
    X(56) X(57) X(58) X(59) X(60) X(61) X(62) X(63)

#define GS(W, I, n, A) { float wn_ = (W)[I]; float tmp_;                         \
    asm("v_fmac_f32 %[a], %[w], %[g]\n\t"                                        \
        "v_mul_f32 %[t], %[w], %[m]\n\t"                                         \
        "v_max_f32 %[g], %[g], %[t]"                                             \
        : [a]"+v"(A), [g]"+v"(g##n), [t]"=&v"(tmp_)                              \
        : [w]"s"(wn_), [m]"v"(mh)); }

__global__ __launch_bounds__(256)
__attribute__((amdgpu_waves_per_eu(2, 4)))
void k_sweep(const float* __restrict__ xn,
             const float* __restrict__ tn,
             float* __restrict__ r_part) {
    int bid = blockIdx.x;
    int cc = bid & 15, ng = (bid >> 4) & 3, b = (bid >> 6) & 7, state = bid >> 9;
    int tid = threadIdx.x;
    int lane = tid & 63;
    int wid = __builtin_amdgcn_readfirstlane(tid >> 6);
    int nc = ng * 4 + wid;                  // wave's row chunk
    int col = cc * 64 + lane;

    __shared__ float red[2][256];

    REP64(GI)

    const float* wb  = xn + (size_t)b * TT * NN + nc * 64;         // wave-uniform rows
    const float* mvb = (state ? tn : xn) + (size_t)b * TT * NN + col;
    float* rp = r_part + ((size_t)((state * 8 + b) * 4 + ng) * TT) * NN + col;

    f16v H1a, H1b, H2a, H2b;
    asm volatile("s_load_dwordx16 %0, %2, 0x0\n\t"
                 "s_load_dwordx16 %1, %2, 0x40"
                 : "=s"(H1a), "=s"(H1b) : "s"(wb));

    float mv_cur = mvb[0];

#pragma unroll 1
    for (int t = 0; t < TT; t++) {
        const float* xrow = wb + (size_t)t * NN;
        int tn1 = (t + 1 < TT) ? t + 1 : TT - 1;
        const float* xrow_n = wb + (size_t)tn1 * NN;
        float mv_nxt = mvb[(size_t)tn1 * NN];
        float sc = (t < TT - 1) ? 0.5f : 0.0f;
        float mh = mv_cur * sc;
        float a0 = 0.f, a1 = 0.f, a2 = 0.f, a3 = 0.f;

        asm volatile("s_waitcnt lgkmcnt(0)" : "+s"(H1a), "+s"(H1b));
        asm volatile("s_load_dwordx16 %0, %2, 0x80\n\t"
                     "s_load_dwordx16 %1, %2, 0xc0"
                     : "=s"(H2a), "=s"(H2b) : "s"(xrow));

        GS(H1a,0,0,a0)   GS(H1a,1,1,a1)   GS(H1a,2,2,a2)   GS(H1a,3,3,a3)
        GS(H1a,4,4,a0)   GS(H1a,5,5,a1)   GS(H1a,6,6,a2)   GS(H1a,7,7,a3)
        GS(H1a,8,8,a0)   GS(H1a,9,9,a1)   GS(H1a,10,10,a2) GS(H1a,11,11,a3)
        GS(H1a,12,12,a0) GS(H1a,13,13,a1) GS(H1a,14,14,a2) GS(H1a,15,15,a3)
        GS(H1b,0,16,a0)  GS(H1b,1,17,a1)  GS(H1b,2,18,a2)  GS(H1b,3,19,a3)
        GS(H1b,4,20,a0)  GS(H1b,5,21,a1)  GS(H1b,6,22,a2)  GS(H1b,7,23,a3)
        GS(H1b,8,24,a0)  GS(H1b,9,25,a1)  GS(H1b,10,26,a2) GS(H1b,11,27,a3)
        GS(H1b,12,28,a0) GS(H1b,13,29,a1) GS(H1b,14,30,a2) GS(H1b,15,31,a3)

        asm volatile("s_waitcnt lgkmcnt(0)"
                     : "+s"(H2a), "+s"(H2b), "+v"(a0), "+v"(a1), "+v"(a2), "+v"(a3));
        asm volatile("s_load_dwordx16 %0, %2, 0x0\n\t"
                     "s_load_dwordx16 %1, %2, 0x40"
                     : "=s"(H1a), "=s"(H1b) : "s"(xrow_n));

        GS(H2a,0,32,a0)  GS(H2a,1,33,a1)  GS(H2a,2,34,a2)  GS(H2a,3,35,a3)
        GS(H2a,4,36,a0)  GS(H2a,5,37,a1)  GS(H2a,6,38,a2)  GS(H2a,7,39,a3)
        GS(H2a,8,40,a0)  GS(H2a,9,41,a1)  GS(H2a,10,42,a2) GS(H2a,11,43,a3)
        GS(H2a,12,44,a0) GS(H2a,13,45,a1) GS(H2a,14,46,a2) GS(H2a,15,47,a3)
        GS(H2b,0,48,a0)  GS(H2b,1,49,a1)  GS(H2b,2,50,a2)  GS(H2b,3,51,a3)
        GS(H2b,4,52,a0)  GS(H2b,5,53,a1)  GS(H2b,6,54,a2)  GS(H2b,7,55,a3)
        GS(H2b,8,56,a0)  GS(H2b,9,57,a1)  GS(H2b,10,58,a2) GS(H2b,11,59,a3)
        GS(H2b,12,60,a0) GS(H2b,13,61,a1) GS(H2b,14,62,a2) GS(H2b,15,63,a3)

        red[t & 1][tid] = (a0 + a1) + (a2 + a3);
        __syncthreads();
        if (wid == 0) {
            const float* r = red[t & 1];
            rp[(size_t)t * NN] = (r[lane] + r[64 + lane]) + (r[128 + lane] + r[192 + lane]);
        }
        mv_cur = mv_nxt;
    }
}

// ---------- reduce partials over ng + mix (round-17 exact) ----------
__global__ __launch_bounds__(256) void k_mix(const float* __restrict__ r_part,
                                             const float* __restrict__ mixp,
                                             float* __restrict__ mix) {
    int bt = blockIdx.x;            // b*TT + t
    int b = bt / TT, t = bt % TT;
    int tid = threadIdx.x;
    int c0 = tid * 4;
    float alpha = 1.f / (1.f + expf(-mixp[0]));

    float spx = 0.f, spy = 0.f, spz = 0.f, spw = 0.f;
    float stx = 0.f, sty = 0.f, stz = 0.f, stw = 0.f;
#pragma unroll
    for (int ng = 0; ng < 4; ng++) {
        int bidp = (b * 4 + ng);
        int bidt = ((8 + b) * 4 + ng);
        float4 p = *reinterpret_cast<const float4*>(r_part + ((size_t)bidp * TT + t) * NN + c0);
        float4 q = *reinterpret_cast<const float4*>(r_part + ((size_t)bidt * TT + t) * NN + c0);
        spx += p.x; spy += p.y; spz += p.z; spw += p.w;
        stx += q.x; sty += q.y; stz += q.z; stw += q.w;
    }
    float4 m4;
    m4.x = alpha * spx + (1.f - alpha) * stx;
    m4.y = alpha * spy + (1.f - alpha) * sty;
    m4.z = alpha * spz + (1.f - alpha) * stz;
    m4.w = alpha * spw + (1.f - alpha) * stw;
    *reinterpret_cast<float4*>(mix + (size_t)bt * NN + c0) = m4;
}

// ---------- y = relu(mix @ Dy) (round-11 exact) ----------
__global__ __launch_bounds__(256) void k_y2(const float* __restrict__ mix,
                                            const float* __restrict__ Dy,
                                            float* __restrict__ out) {
    int ct = blockIdx.x;            // 0..7
    int rt = blockIdx.y;            // 0..23
    int tid = threadIdx.x;
    int row0 = rt * 16;
    int col0 = ct * 64;
    int r = tid >> 4;
    int tc = tid & 15;

    __shared__ float As[16][16];
    __shared__ float Ds[16][64];

    int sr = tid >> 4, sk = tid & 15;
    int se = tid >> 4, sc0 = (tid & 15) * 4;

    float4 acc = make_float4(0.f, 0.f, 0.f, 0.f);

    for (int m0 = 0; m0 < NN; m0 += 16) {
        float av = mix[(size_t)(row0 + sr) * NN + m0 + sk];
        float4 dv = *reinterpret_cast<const float4*>(Dy + (size_t)(m0 + se) * DD + col0 + sc0);
        __syncthreads();
        As[sr][sk] = av;
        *reinterpret_cast<float4*>(&Ds[se][sc0]) = dv;
        __syncthreads();
#pragma unroll
        for (int k = 0; k < 16; k++) {
            float a = As[r][k];
            float4 e = *reinterpret_cast<const float4*>(&Ds[k][tc * 4]);
            acc.x = fmaf(a, e.x, acc.x);
            acc.y = fmaf(a, e.y, acc.y);
            acc.z = fmaf(a, e.z, acc.z);
            acc.w = fmaf(a, e.w, acc.w);
        }
    }

    float4 o = make_float4(fmaxf(acc.x, 0.f), fmaxf(acc.y, 0.f),
                           fmaxf(acc.z, 0.f), fmaxf(acc.w, 0.f));
    *reinterpret_cast<float4*>(out + (size_t)(row0 + r) * DD + col0 + tc * 4) = o;
}

extern "C" void kernel_launch(void* const* d_in, const int* in_sizes, int n_in,
                              void* d_out, int out_size, void* d_ws, size_t ws_size,
                              hipStream_t stream) {
    const float* x    = (const float*)d_in[0];   // [8,48,512]
    const float* tg   = (const float*)d_in[1];   // [8,48,512]
    const float* E    = (const float*)d_in[2];   // [512,1024]
    const float* Dy   = (const float*)d_in[3];   // [1024,512]
    const float* mixp = (const float*)d_in[4];   // scalar
    float* out = (float*)d_out;                  // [8,48,512]

    float* ws = (float*)d_ws;
    float* z_x    = ws;                               // 384*1024
    float* z_t    = z_x + (size_t)384 * 1024;
    float* xn     = z_t + (size_t)384 * 1024;
    float* tn     = xn + (size_t)384 * 1024;
    float* r_part = tn + (size_t)384 * 1024;          // 64 chunks * 48 * 1024 floats
    float* mixbuf = r_part + (size_t)64 * 48 * 1024;  // 384*1024

    k_gemm_z<<<dim3(24, 16), 256, 0, stream>>>(x, tg, E, z_x, z_t);
    k_ln<<<384, 256, 0, stream>>>(z_x, z_t, xn, tn);
    k_sweep<<<1024, 256, 0, stream>>>(xn, tn, r_part);
    k_mix<<<384, 256, 0, stream>>>(r_part, mixp, mixbuf);
    k_y2<<<dim3(8, 24), 256, 0, stream>>>(mixbuf, Dy, out);
}